// Round 1
// baseline (41.604 us; speedup 1.0000x reference)
//
#include <hip/hip_runtime.h>

// LengthRegulator: B=32, S=512, D=512, T(max_mel)=2048
// out = [padded (B*T*D f32)] ++ [d (B*S, written as float values)]

#define BB 32
#define SS 512
#define DD 512
#define TT 2048
#define SLOWDOWN 0.5f

// One block (512 threads) per batch:
//  - compute d_i, write d output (as float)
//  - inclusive scan of d_i in LDS (Hillis-Steele, 9 steps)
//  - scatter token index into frame_tok[b][t] for t in [csum-d, min(csum,T))
//  - frames >= total stay at sentinel SS (pad)
__global__ __launch_bounds__(SS)
void lr_scan_scatter(const float* __restrict__ durations,
                     float* __restrict__ d_out_tail,
                     int* __restrict__ frame_tok) {
    const int b   = blockIdx.x;
    const int tid = threadIdx.x;              // 0..511 == token index

    // init frame->token map to sentinel (pad)
    int* ft = frame_tok + (size_t)b * TT;
#pragma unroll
    for (int i = 0; i < TT / SS; ++i) ft[tid + i * SS] = SS;

    // d_i = trunc(max(dur + 0.5, 1))  (positive -> trunc == floor)
    float df = durations[b * SS + tid] + SLOWDOWN;
    df = fmaxf(df, 1.0f);
    int di = (int)df;
    d_out_tail[b * SS + tid] = (float)di;

    __shared__ int sa[SS], sb[SS];
    sa[tid] = di;
    __syncthreads();                          // also orders the ft[] init writes
    int* src = sa;
    int* dst = sb;
    for (int off = 1; off < SS; off <<= 1) {
        int v = src[tid];
        if (tid >= off) v += src[tid - off];
        dst[tid] = v;
        __syncthreads();
        int* tmp = src; src = dst; dst = tmp;
    }
    const int csum  = src[tid];               // inclusive end offset
    const int start = csum - di;

    if (start < TT) {
        const int end = (csum < TT) ? csum : TT;
        for (int f = start; f < end; ++f) ft[f] = tid;   // disjoint ranges per token
    }
}

// One 256-thread block handles 2 output frames; 128 threads (float4 each)
// copy one D=512 row (2 KB) from sequences or write zeros.
__global__ __launch_bounds__(256)
void lr_gather(const float* __restrict__ seq,
               const int* __restrict__ frame_tok,
               float* __restrict__ out) {
    const int frame = blockIdx.x * 2 + (threadIdx.x >> 7);   // global frame id b*T+t
    const int lane  = threadIdx.x & 127;                     // 0..127
    const int b     = frame >> 11;                           // frame / TT
    const int tok   = frame_tok[frame];

    float4* o = reinterpret_cast<float4*>(out + (size_t)frame * DD);
    if (tok < SS) {
        const float4* s4 = reinterpret_cast<const float4*>(
            seq + ((size_t)b * SS + tok) * DD);
        o[lane] = s4[lane];
    } else {
        o[lane] = make_float4(0.f, 0.f, 0.f, 0.f);
    }
}

extern "C" void kernel_launch(void* const* d_in, const int* in_sizes, int n_in,
                              void* d_out, int out_size, void* d_ws, size_t ws_size,
                              hipStream_t stream) {
    const float* sequences = (const float*)d_in[0];   // [B,S,D] f32
    const float* durations = (const float*)d_in[1];   // [B,S]   f32
    // d_in[2] = max_mel_length scalar (fixed 2048, compile-time)

    float* out        = (float*)d_out;
    float* d_out_tail = out + (size_t)BB * TT * DD;   // second output: d as floats
    int*   frame_tok  = (int*)d_ws;                   // B*T ints = 256 KB

    lr_scan_scatter<<<BB, SS, 0, stream>>>(durations, d_out_tail, frame_tok);
    lr_gather<<<(BB * TT) / 2, 256, 0, stream>>>(sequences, frame_tok, out);
}

// Round 2
// 36.448 us; speedup vs baseline: 1.1415x; 1.1415x over previous
//
#include <hip/hip_runtime.h>

// LengthRegulator: B=32, S=512, D=512, T(max_mel)=2048
// out = [padded (B*T*D f32)] ++ [d (B*S, written as float values)]

#define BB 32
#define SS 512
#define DD 512
#define TT 2048
#define SLOWDOWN 0.5f
#define FPB 32   // frames per gather block (divides TT)

// One block (512 threads) per batch:
//  - compute d_i, write d output (as float)
//  - inclusive scan: shfl wave-scan (6 steps) + cross-wave LDS combine (1 barrier)
//  - scatter token index into frame_tok[b][t] for t in [csum-d, min(csum,T))
//  - frames >= total stay at sentinel SS (pad)
__global__ __launch_bounds__(SS)
void lr_scan_scatter(const float* __restrict__ durations,
                     float* __restrict__ d_out_tail,
                     int* __restrict__ frame_tok) {
    const int b    = blockIdx.x;
    const int tid  = threadIdx.x;             // 0..511 == token index
    const int lane = tid & 63;
    const int wv   = tid >> 6;                // 0..7

    // init frame->token map to sentinel (pad)
    int* ft = frame_tok + (size_t)b * TT;
#pragma unroll
    for (int i = 0; i < TT / SS; ++i) ft[tid + i * SS] = SS;

    // d_i = trunc(max(dur + 0.5, 1))  (positive -> trunc == floor)
    float df = durations[b * SS + tid] + SLOWDOWN;
    df = fmaxf(df, 1.0f);
    int di = (int)df;
    d_out_tail[b * SS + tid] = (float)di;

    // wave-level inclusive scan (64 lanes, 6 shuffle steps)
    int v = di;
#pragma unroll
    for (int off = 1; off < 64; off <<= 1) {
        int n = __shfl_up(v, off);
        if (lane >= off) v += n;
    }
    __shared__ int wtot[8];
    if (lane == 63) wtot[wv] = v;
    __syncthreads();   // publishes wtot AND orders ft[] init before scatter
    int woff = 0;
#pragma unroll
    for (int w = 0; w < 7; ++w) woff += (w < wv) ? wtot[w] : 0;

    const int csum  = v + woff;               // inclusive end offset
    const int start = csum - di;
    if (start < TT) {
        const int end = (csum < TT) ? csum : TT;
        for (int f = start; f < end; ++f) ft[f] = tid;   // disjoint ranges per token
    }
}

// 256-thread block handles FPB=32 consecutive frames (64 KB out).
// frame_tok for the block is staged in LDS once; copy loop has 8 independent
// frame-copies in flight (unroll 4 x 2 frames/pass) for latency hiding.
__global__ __launch_bounds__(256)
void lr_gather(const float* __restrict__ seq,
               const int* __restrict__ frame_tok,
               float* __restrict__ out) {
    const int tid   = threadIdx.x;
    const int fbase = blockIdx.x * FPB;       // global frame id b*T + t
    __shared__ int stok[FPB];
    if (tid < FPB) stok[tid] = frame_tok[fbase + tid];
    __syncthreads();

    const int sub  = tid >> 7;                // 0..1: which frame of the pair
    const int lane = tid & 127;               // float4 lane within row (D=512 -> 128)
    const int b    = fbase >> 11;             // TT=2048; FPB|TT so whole block same batch
    const float* sbase = seq + (size_t)b * SS * DD;

#pragma unroll 4
    for (int p = 0; p < FPB / 2; ++p) {
        const int fi  = p * 2 + sub;          // frame index within block
        const int tok = stok[fi];             // broadcast read, conflict-free
        float4* o = reinterpret_cast<float4*>(out + (size_t)(fbase + fi) * DD);
        if (tok < SS) {
            const float4* s4 = reinterpret_cast<const float4*>(sbase + (size_t)tok * DD);
            o[lane] = s4[lane];
        } else {
            o[lane] = make_float4(0.f, 0.f, 0.f, 0.f);
        }
    }
}

extern "C" void kernel_launch(void* const* d_in, const int* in_sizes, int n_in,
                              void* d_out, int out_size, void* d_ws, size_t ws_size,
                              hipStream_t stream) {
    const float* sequences = (const float*)d_in[0];   // [B,S,D] f32
    const float* durations = (const float*)d_in[1];   // [B,S]   f32
    // d_in[2] = max_mel_length scalar (fixed 2048, compile-time)

    float* out        = (float*)d_out;
    float* d_out_tail = out + (size_t)BB * TT * DD;   // second output: d as floats
    int*   frame_tok  = (int*)d_ws;                   // B*T ints = 256 KB

    lr_scan_scatter<<<BB, SS, 0, stream>>>(durations, d_out_tail, frame_tok);
    lr_gather<<<(BB * TT) / FPB, 256, 0, stream>>>(sequences, frame_tok, out);
}

// Round 3
// 32.435 us; speedup vs baseline: 1.2827x; 1.1237x over previous
//
#include <hip/hip_runtime.h>

// LengthRegulator fused single-kernel: B=32, S=512, D=512, T(max_mel)=2048
// out = [padded (B*T*D f32)] ++ [d (B*S, written as float values)]
//
// Each block owns FPB=32 consecutive output frames of one batch. It
// recomputes the batch's duration cumsum in LDS (cheap: 2 KB input),
// binary-searches its frames' token indices, then does the row copies.
// No inter-kernel dependency, no workspace.

#define BB 32
#define SS 512
#define DD 512
#define TT 2048
#define SLOWDOWN 0.5f
#define FPB 32            // frames per block; TT/FPB = 64 chunks per batch

__global__ __launch_bounds__(256)
void lr_fused(const float* __restrict__ durations,
              const float* __restrict__ seq,
              float* __restrict__ out,
              float* __restrict__ d_out_tail) {
    const int blk   = blockIdx.x;
    const int b     = blk >> 6;           // blk / (TT/FPB)
    const int chunk = blk & 63;
    const int tbase = chunk * FPB;        // first frame this block writes
    const int tid   = threadIdx.x;        // 0..255
    const int lane  = tid & 63;
    const int wv    = tid >> 6;           // 0..3

    __shared__ int csum[SS];
    __shared__ int wtot[4];
    __shared__ int stok[FPB];

    // ---- recompute duration scan for batch b (2 tokens per thread) ----
    const float2 dur = *reinterpret_cast<const float2*>(durations + b * SS + tid * 2);
    const int d0 = (int)fmaxf(dur.x + SLOWDOWN, 1.0f);   // trunc == floor (>=1)
    const int d1 = (int)fmaxf(dur.y + SLOWDOWN, 1.0f);

    int v = d0 + d1;                      // pair sum -> wave inclusive scan
#pragma unroll
    for (int off = 1; off < 64; off <<= 1) {
        int n = __shfl_up(v, off);
        if (lane >= off) v += n;
    }
    if (lane == 63) wtot[wv] = v;
    __syncthreads();
    int woff = 0;
#pragma unroll
    for (int w = 0; w < 3; ++w) woff += (w < wv) ? wtot[w] : 0;

    const int c1 = v + woff;              // inclusive csum through token 2*tid+1
    csum[2 * tid]     = c1 - d1;          // inclusive csum through token 2*tid
    csum[2 * tid + 1] = c1;

    if (chunk == 0) {                     // one block per batch emits d
        d_out_tail[b * SS + 2 * tid]     = (float)d0;
        d_out_tail[b * SS + 2 * tid + 1] = (float)d1;
    }
    __syncthreads();

    // ---- token index per frame: idx = #(csum <= t) (searchsorted right) ----
    if (tid < FPB) {
        const int t = tbase + tid;
        int lo = 0, hi = SS;
        while (lo < hi) {
            const int mid = (lo + hi) >> 1;
            if (csum[mid] <= t) lo = mid + 1; else hi = mid;
        }
        stok[tid] = lo;                   // == SS when t >= total (pad)
    }
    __syncthreads();

    // ---- row copies: 2 frames in parallel, 128 float4 lanes per row ----
    const int sub  = tid >> 7;            // which frame of the pair
    const int l    = tid & 127;
    const float* sbase = seq + (size_t)b * SS * DD;
    float* obase = out + ((size_t)b * TT + tbase) * DD;

#pragma unroll 4
    for (int p = 0; p < FPB / 2; ++p) {
        const int fi  = p * 2 + sub;
        const int tok = stok[fi];         // broadcast
        float4* o = reinterpret_cast<float4*>(obase + (size_t)fi * DD);
        if (tok < SS) {
            const float4* s4 = reinterpret_cast<const float4*>(sbase + (size_t)tok * DD);
            o[l] = s4[l];
        } else {
            o[l] = make_float4(0.f, 0.f, 0.f, 0.f);
        }
    }
}

extern "C" void kernel_launch(void* const* d_in, const int* in_sizes, int n_in,
                              void* d_out, int out_size, void* d_ws, size_t ws_size,
                              hipStream_t stream) {
    const float* sequences = (const float*)d_in[0];   // [B,S,D] f32
    const float* durations = (const float*)d_in[1];   // [B,S]   f32
    // d_in[2] = max_mel_length scalar (fixed 2048, compile-time)

    float* out        = (float*)d_out;
    float* d_out_tail = out + (size_t)BB * TT * DD;   // second output: d as floats

    lr_fused<<<BB * (TT / FPB), 256, 0, stream>>>(durations, sequences, out, d_out_tail);
}

// Round 4
// 31.044 us; speedup vs baseline: 1.3402x; 1.0448x over previous
//
#include <hip/hip_runtime.h>

// LengthRegulator fused single-kernel: B=32, S=512, D=512, T(max_mel)=2048
// out = [padded (B*T*D f32)] ++ [d (B*S, written as float values)]
//
// Each block owns FPB=64 consecutive output frames of one batch (128 KB out).
// It recomputes the batch's duration cumsum in LDS (2 KB input), binary-
// searches its frames' token indices, then streams the row copies with
// non-temporal stores (writes are never re-read -> don't pollute L2).

#define BB 32
#define SS 512
#define DD 512
#define TT 2048
#define SLOWDOWN 0.5f
#define FPB 64            // frames per block; TT/FPB = 32 chunks per batch

using f32x4 = __attribute__((ext_vector_type(4))) float;

__global__ __launch_bounds__(256)
void lr_fused(const float* __restrict__ durations,
              const float* __restrict__ seq,
              float* __restrict__ out,
              float* __restrict__ d_out_tail) {
    const int blk   = blockIdx.x;
    const int b     = blk >> 5;           // blk / (TT/FPB)
    const int chunk = blk & 31;
    const int tbase = chunk * FPB;        // first frame this block writes
    const int tid   = threadIdx.x;        // 0..255
    const int lane  = tid & 63;
    const int wv    = tid >> 6;           // 0..3

    __shared__ int csum[SS];
    __shared__ int wtot[4];
    __shared__ int stok[FPB];

    // ---- recompute duration scan for batch b (2 tokens per thread) ----
    const float2 dur = *reinterpret_cast<const float2*>(durations + b * SS + tid * 2);
    const int d0 = (int)fmaxf(dur.x + SLOWDOWN, 1.0f);   // trunc == floor (>=1)
    const int d1 = (int)fmaxf(dur.y + SLOWDOWN, 1.0f);

    int v = d0 + d1;                      // pair sum -> wave inclusive scan
#pragma unroll
    for (int off = 1; off < 64; off <<= 1) {
        int n = __shfl_up(v, off);
        if (lane >= off) v += n;
    }
    if (lane == 63) wtot[wv] = v;
    __syncthreads();
    int woff = 0;
#pragma unroll
    for (int w = 0; w < 3; ++w) woff += (w < wv) ? wtot[w] : 0;

    const int c1 = v + woff;              // inclusive csum through token 2*tid+1
    csum[2 * tid]     = c1 - d1;          // inclusive csum through token 2*tid
    csum[2 * tid + 1] = c1;

    if (chunk == 0) {                     // one block per batch emits d
        d_out_tail[b * SS + 2 * tid]     = (float)d0;
        d_out_tail[b * SS + 2 * tid + 1] = (float)d1;
    }
    __syncthreads();

    // ---- token index per frame: idx = #(csum <= t) (searchsorted right) ----
    if (tid < FPB) {
        const int t = tbase + tid;
        int lo = 0, hi = SS;
        while (lo < hi) {
            const int mid = (lo + hi) >> 1;
            if (csum[mid] <= t) lo = mid + 1; else hi = mid;
        }
        stok[tid] = lo;                   // == SS when t >= total (pad)
    }
    __syncthreads();

    // ---- row copies: 2 frames in parallel, 128 f32x4 lanes per row ----
    const int sub  = tid >> 7;            // which frame of the pair
    const int l    = tid & 127;
    const f32x4* sbase = reinterpret_cast<const f32x4*>(seq + (size_t)b * SS * DD) + l;
    f32x4* obase = reinterpret_cast<f32x4*>(out + ((size_t)b * TT + tbase) * DD) + l;

#pragma unroll 8
    for (int p = 0; p < FPB / 2; ++p) {
        const int fi  = p * 2 + sub;
        const int tok = stok[fi];                   // LDS broadcast
        const int tc  = (tok < SS) ? tok : (SS - 1);
        f32x4 r = sbase[(size_t)tc * (DD / 4)];     // branchless: always load
        if (tok >= SS) r = (f32x4){0.f, 0.f, 0.f, 0.f};   // cndmask, no divergence cost
        __builtin_nontemporal_store(r, obase + (size_t)fi * (DD / 4));
    }
}

extern "C" void kernel_launch(void* const* d_in, const int* in_sizes, int n_in,
                              void* d_out, int out_size, void* d_ws, size_t ws_size,
                              hipStream_t stream) {
    const float* sequences = (const float*)d_in[0];   // [B,S,D] f32
    const float* durations = (const float*)d_in[1];   // [B,S]   f32
    // d_in[2] = max_mel_length scalar (fixed 2048, compile-time)

    float* out        = (float*)d_out;
    float* d_out_tail = out + (size_t)BB * TT * DD;   // second output: d as floats

    lr_fused<<<BB * (TT / FPB), 256, 0, stream>>>(durations, sequences, out, d_out_tail);
}

// Round 5
// 30.375 us; speedup vs baseline: 1.3697x; 1.0220x over previous
//
#include <hip/hip_runtime.h>

// LengthRegulator fused single-kernel: B=32, S=512, D=512, T(max_mel)=2048
// out = [padded (B*T*D f32)] ++ [d (B*S, written as float values)]
//
// Each 512-thread block owns FPB=128 consecutive output frames of one batch
// (256 KB out). It recomputes the batch's duration cumsum in LDS (1 token/
// thread), binary-searches its frames' token indices, then streams the row
// copies (4 rows in flight/pass) with non-temporal stores.

#define BB 32
#define SS 512
#define DD 512
#define TT 2048
#define SLOWDOWN 0.5f
#define FPB 128           // frames per block; TT/FPB = 16 chunks per batch

using f32x4 = __attribute__((ext_vector_type(4))) float;

__global__ __launch_bounds__(512)
void lr_fused(const float* __restrict__ durations,
              const float* __restrict__ seq,
              float* __restrict__ out,
              float* __restrict__ d_out_tail) {
    const int blk   = blockIdx.x;
    const int b     = blk >> 4;           // blk / (TT/FPB)
    const int chunk = blk & 15;
    const int tbase = chunk * FPB;        // first frame this block writes
    const int tid   = threadIdx.x;        // 0..511
    const int lane  = tid & 63;
    const int wv    = tid >> 6;           // 0..7

    __shared__ int csum[SS];
    __shared__ int wtot[8];
    __shared__ int stok[FPB];

    // ---- recompute duration scan for batch b (1 token per thread) ----
    const float dur = durations[b * SS + tid];
    const int di = (int)fmaxf(dur + SLOWDOWN, 1.0f);   // trunc == floor (>=1)

    int v = di;                           // wave inclusive scan (6 shuffle steps)
#pragma unroll
    for (int off = 1; off < 64; off <<= 1) {
        int n = __shfl_up(v, off);
        if (lane >= off) v += n;
    }
    if (lane == 63) wtot[wv] = v;
    __syncthreads();
    int woff = 0;
#pragma unroll
    for (int w = 0; w < 7; ++w) woff += (w < wv) ? wtot[w] : 0;

    csum[tid] = v + woff;                 // inclusive csum through token tid

    if (chunk == 0)                       // one block per batch emits d
        d_out_tail[b * SS + tid] = (float)di;
    __syncthreads();

    // ---- token index per frame: idx = #(csum <= t) (searchsorted right) ----
    if (tid < FPB) {
        const int t = tbase + tid;
        int lo = 0, hi = SS;
        while (lo < hi) {
            const int mid = (lo + hi) >> 1;
            if (csum[mid] <= t) lo = mid + 1; else hi = mid;
        }
        stok[tid] = lo;                   // == SS when t >= total (pad)
    }
    __syncthreads();

    // ---- row copies: 4 frames in parallel, 128 f32x4 lanes per row ----
    const int sub = tid >> 7;             // 0..3: which frame of the quad
    const int l   = tid & 127;
    const f32x4* sbase = reinterpret_cast<const f32x4*>(seq + (size_t)b * SS * DD) + l;
    f32x4* obase = reinterpret_cast<f32x4*>(out + ((size_t)b * TT + tbase) * DD) + l;

#pragma unroll 8
    for (int p = 0; p < FPB / 4; ++p) {
        const int fi  = p * 4 + sub;
        const int tok = stok[fi];                   // LDS broadcast
        const int tc  = (tok < SS) ? tok : (SS - 1);
        f32x4 r = sbase[(size_t)tc * (DD / 4)];     // branchless: always load
        if (tok >= SS) r = (f32x4){0.f, 0.f, 0.f, 0.f};
        __builtin_nontemporal_store(r, obase + (size_t)fi * (DD / 4));
    }
}

extern "C" void kernel_launch(void* const* d_in, const int* in_sizes, int n_in,
                              void* d_out, int out_size, void* d_ws, size_t ws_size,
                              hipStream_t stream) {
    const float* sequences = (const float*)d_in[0];   // [B,S,D] f32
    const float* durations = (const float*)d_in[1];   // [B,S]   f32
    // d_in[2] = max_mel_length scalar (fixed 2048, compile-time)

    float* out        = (float*)d_out;
    float* d_out_tail = out + (size_t)BB * TT * DD;   // second output: d as floats

    lr_fused<<<BB * (TT / FPB), 512, 0, stream>>>(durations, sequences, out, d_out_tail);
}

// Round 6
// 29.867 us; speedup vs baseline: 1.3930x; 1.0170x over previous
//
#include <hip/hip_runtime.h>

// LengthRegulator fused single-kernel: B=32, S=512, D=512, T(max_mel)=2048
// out = [padded (B*T*D f32)] ++ [d (B*S, written as float values)]
//
// Each 512-thread block owns FPB=128 consecutive output frames of one batch.
// Prologue (shortened critical path): durations load -> shfl scan -> barrier
// -> per-thread SCATTER of token id into the block's stok[] window (each
// thread knows its own [csum-di, csum) span; di<=8) -> barrier -> row copies
// with non-temporal stores. No csum array, no binary search.

#define BB 32
#define SS 512
#define DD 512
#define TT 2048
#define SLOWDOWN 0.5f
#define FPB 128           // frames per block; TT/FPB = 16 chunks per batch

using f32x4 = __attribute__((ext_vector_type(4))) float;

__global__ __launch_bounds__(512)
void lr_fused(const float* __restrict__ durations,
              const float* __restrict__ seq,
              float* __restrict__ out,
              float* __restrict__ d_out_tail) {
    const int blk   = blockIdx.x;
    const int b     = blk >> 4;           // blk / (TT/FPB)
    const int chunk = blk & 15;
    const int tbase = chunk * FPB;        // first frame this block writes
    const int tid   = threadIdx.x;        // 0..511 == token index
    const int lane  = tid & 63;
    const int wv    = tid >> 6;           // 0..7

    __shared__ int stok[FPB];
    __shared__ int wtot[8];

    if (tid < FPB) stok[tid] = SS;        // pad sentinel; published by barrier 1

    // ---- duration + inclusive scan for batch b (1 token per thread) ----
    const float dur = durations[b * SS + tid];
    const int di = (int)fmaxf(dur + SLOWDOWN, 1.0f);   // trunc == floor; di in [1,8]

    int v = di;                           // wave inclusive scan (6 shuffle steps)
#pragma unroll
    for (int off = 1; off < 64; off <<= 1) {
        int n = __shfl_up(v, off);
        if (lane >= off) v += n;
    }
    if (lane == 63) wtot[wv] = v;

    if (chunk == 0)                       // one block per batch emits d
        d_out_tail[b * SS + tid] = (float)di;

    __syncthreads();                      // barrier 1: wtot + stok init visible
    int woff = 0;
#pragma unroll
    for (int w = 0; w < 7; ++w) woff += (w < wv) ? wtot[w] : 0;

    const int csum  = v + woff;           // inclusive end offset of token tid
    // ---- scatter: frames [csum-di, csum) ∩ [tbase, tbase+FPB) -> token tid ----
    {
        int f0 = csum - di; if (f0 < tbase) f0 = tbase;
        int f1 = csum;      if (f1 > tbase + FPB) f1 = tbase + FPB;
        for (int f = f0; f < f1; ++f) stok[f - tbase] = tid;   // disjoint addrs
    }
    __syncthreads();                      // barrier 2: stok ready

    // ---- row copies: 4 frames in parallel, 128 f32x4 lanes per row ----
    const int sub = tid >> 7;             // 0..3: which frame of the quad
    const int l   = tid & 127;
    const f32x4* sbase = reinterpret_cast<const f32x4*>(seq + (size_t)b * SS * DD) + l;
    f32x4* obase = reinterpret_cast<f32x4*>(out + ((size_t)b * TT + tbase) * DD) + l;

#pragma unroll 8
    for (int p = 0; p < FPB / 4; ++p) {
        const int fi  = p * 4 + sub;
        const int tok = stok[fi];                   // LDS broadcast
        const int tc  = (tok < SS) ? tok : (SS - 1);
        f32x4 r = sbase[(size_t)tc * (DD / 4)];     // branchless: always load
        if (tok >= SS) r = (f32x4){0.f, 0.f, 0.f, 0.f};
        __builtin_nontemporal_store(r, obase + (size_t)fi * (DD / 4));
    }
}

extern "C" void kernel_launch(void* const* d_in, const int* in_sizes, int n_in,
                              void* d_out, int out_size, void* d_ws, size_t ws_size,
                              hipStream_t stream) {
    const float* sequences = (const float*)d_in[0];   // [B,S,D] f32
    const float* durations = (const float*)d_in[1];   // [B,S]   f32
    // d_in[2] = max_mel_length scalar (fixed 2048, compile-time)

    float* out        = (float*)d_out;
    float* d_out_tail = out + (size_t)BB * TT * DD;   // second output: d as floats

    lr_fused<<<BB * (TT / FPB), 512, 0, stream>>>(durations, sequences, out, d_out_tail);
}